// Round 1
// baseline (465.615 us; speedup 1.0000x reference)
//
#include <hip/hip_runtime.h>
#include <hip/hip_bf16.h>

// Problem constants
#define BB 256
#define TT 1024
#define II 128
#define HH 64

// 2/ln2 folded into W_comm, W_in and biases at prep time, so the recurrence
// computes tanh(x) as 1 - 2/(1+exp2(acc)) with no per-step pre-multiply.
#define PRESCALE 2.8853900817779268f

typedef float    f32x4_t __attribute__((ext_vector_type(4)));
typedef _Float16 h16x2   __attribute__((ext_vector_type(2)));
typedef _Float16 h16x4   __attribute__((ext_vector_type(4)));
typedef _Float16 h16x8   __attribute__((ext_vector_type(8)));
typedef __fp16   p16x2   __attribute__((ext_vector_type(2)));

union UH2 { unsigned u; h16x2 h; p16x2 p; };
union U4H8 { uint4 u; h16x8 h; };

__device__ __forceinline__ float tanh_pre(float a){
  // input pre-scaled by 2/ln2: tanh = 1 - 2/(1+2^a)
  float e = __builtin_amdgcn_exp2f(a);
  return __builtin_fmaf(-2.0f, __builtin_amdgcn_rcpf(1.0f + e), 1.0f);
}

#if __has_builtin(__builtin_amdgcn_fdot2)
__device__ __forceinline__ float fdot2f(h16x2 a, h16x2 b, float c){
  return __builtin_amdgcn_fdot2(a, b, c, false);
}
#else
__device__ __forceinline__ float fdot2f(h16x2 a, h16x2 b, float c){
  return __builtin_fmaf((float)a[1], (float)b[1], __builtin_fmaf((float)a[0], (float)b[0], c));
}
#endif

// ---------------------------------------------------------------------------
// Workspace layout:
//   wsf (f32)  @ 0      [4160]: W_comm 64x64 row-major + combined bias[64] (all x PRESCALE)
//   whf (u32)  @ 16640  [2048]: W_comm rows as packed f16x2 pairs
//   wsb (u16)  @ 24832  [8192]: W_in f16 MFMA B-fragments, frag-ready (x PRESCALE)
// ---------------------------------------------------------------------------
__global__ void k_prep(const float* __restrict__ Ap, const float* __restrict__ Am,
                       const float* __restrict__ Winw,
                       const float* __restrict__ Winb, const float* __restrict__ bias,
                       float* __restrict__ wsf, unsigned* __restrict__ whf,
                       unsigned short* __restrict__ wsb){
  const int tid = threadIdx.x;
  for (int e = tid; e < 4096; e += 256){
    int i = e >> 6, j = e & 63;
    int is = i ^ 32, js = j ^ 32;
    float wp = Ap[i*64+j] + Ap[i*64+js] + Ap[is*64+j] + Ap[is*64+js];
    float wm = Am[i*64+j] - Am[i*64+js] - Am[is*64+j] + Am[is*64+js];
    wsf[e] = 0.25f * (wp + wm) * PRESCALE;
  }
  if (tid < 64) wsf[4096 + tid] = (Winb[tid] + bias[tid]) * PRESCALE;
  for (int e = tid; e < 8192; e += 256){
    int j = e & 7, lane = (e >> 3) & 63, fidx = e >> 9;
    int ks = fidx >> 2, nt = fidx & 3, l15 = lane & 15, q = lane >> 4;
    union { _Float16 f; unsigned short s; } cv;
    cv.f = (_Float16)(Winw[(nt*16 + l15)*II + ks*32 + q*8 + j] * PRESCALE);
    wsb[e] = cv.s;
  }
  __syncthreads();
  for (int e = tid; e < 2048; e += 256){
    int i = e >> 5, jp = e & 31;
    UH2 p;
    p.h[0] = (_Float16)wsf[i*64 + 2*jp];
    p.h[1] = (_Float16)wsf[i*64 + 2*jp + 1];
    whf[e] = p.u;
  }
}

// ---------------------------------------------------------------------------
// Fused producer/consumer kernel, TLP version: 128 blocks x 512 threads,
// each block owns TWO batch elements. Waves map to SIMDs as wave%4, so
// waves 0 and 4 are BOTH on SIMD0: two independent recurrence chains
// interleave in hardware, filling the single-wave issue-cadence and
// dep-latency stalls that left SIMD0 ~63% idle in the 1-chain version.
//   Consumers: wave 0 -> batch 2b+0, wave 4 -> batch 2b+1.
//   Producers: waves 1,2,3 feed batch 0; waves 5,6,7 feed batch 1
//              (same 3-waves-per-batch production rate as before).
// LDS: u ring buffer, 32 tiles (= 512 timesteps) per batch, 2 x 64 KB.
//   Producer of tile t>30 waits until its consumer has completed tile t-30
//   (consumer reads at most 1 tile ahead -> 2-tile safety margin on the
//   32-slot ring). Consumer publishes progress once per tile (release store,
//   which also drains its outstanding LDS reads before slots may be reused).
// ---------------------------------------------------------------------------
__global__ __launch_bounds__(512, 1) void k_fused(const float* __restrict__ x,
                                                  const float* __restrict__ wsf,
                                                  const unsigned* __restrict__ whf,
                                                  const unsigned short* __restrict__ wsb,
                                                  const float* __restrict__ Wout,
                                                  const float* __restrict__ Woutb,
                                                  float* __restrict__ out){
  extern __shared__ unsigned char smem[];
  unsigned short* Us    = (unsigned short*)smem;          // 2 x 64 KB u ring
  unsigned*       flags = (unsigned*)(smem + 131072);     // [0..127] tile flags, [128..129] cons counters
  unsigned*       cons  = flags + 128;

  const int tid  = threadIdx.x;
  const int lane = tid & 63;
  const int wave = tid >> 6;
  const int l15  = lane & 15;
  const int q    = lane >> 4;
  const int sel  = (wave >= 4) ? 1 : 0;   // which batch of the pair

  if (tid < 130) flags[tid] = 0u;
  __syncthreads();

  unsigned* flg = flags + sel*64;

  if ((wave & 3) != 0){
    // ---------------- Producers: waves 1,2,3 (sel=0) / 5,6,7 (sel=1) -------
    const int p = (wave & 3) - 1;   // 0..2 within this batch's producer trio
    h16x8 bfr[4][4]; // [ks][nt]
    #pragma unroll
    for (int ks = 0; ks < 4; ++ks)
      #pragma unroll
      for (int nt = 0; nt < 4; ++nt)
        bfr[ks][nt] = *(const h16x8*)(wsb + ((ks*4 + nt)*64 + lane)*8);

    float bcv[4];
    #pragma unroll
    for (int nt = 0; nt < 4; ++nt) bcv[nt] = wsf[4096 + nt*16 + l15];

    const float* xb = x + (long)(2*blockIdx.x + sel) * (TT * II);
    unsigned short* Ub = Us + sel * 32768;   // 64 KB region, u16 units

    #pragma unroll 1
    for (int tile = p; tile < 64; tile += 3){
      if (tile > 30){
        // ring safety: don't overwrite slot (tile%32) until consumer is done
        // with tile-32 and past tile-31 (margin: wait for cons >= tile-30)
        while (__hip_atomic_load(&cons[sel], __ATOMIC_ACQUIRE, __HIP_MEMORY_SCOPE_WORKGROUP) + 30u < (unsigned)tile) {}
      }
      const int trow = tile * 16;
      const float* xa = xb + (trow + l15) * II + q*8;
      h16x8 afr[4];
      #pragma unroll
      for (int ks = 0; ks < 4; ++ks){
        float4 a0 = *(const float4*)(xa + ks*32);
        float4 a1 = *(const float4*)(xa + ks*32 + 4);
        U4H8 v;
        UH2 p0, p1, p2, p3;
        p0.p = __builtin_amdgcn_cvt_pkrtz(a0.x, a0.y);
        p1.p = __builtin_amdgcn_cvt_pkrtz(a0.z, a0.w);
        p2.p = __builtin_amdgcn_cvt_pkrtz(a1.x, a1.y);
        p3.p = __builtin_amdgcn_cvt_pkrtz(a1.z, a1.w);
        v.u.x = p0.u; v.u.y = p1.u; v.u.z = p2.u; v.u.w = p3.u;
        afr[ks] = v.h;
      }
      f32x4_t acc[4];
      #pragma unroll
      for (int nt = 0; nt < 4; ++nt){
        acc[nt][0]=bcv[nt]; acc[nt][1]=bcv[nt]; acc[nt][2]=bcv[nt]; acc[nt][3]=bcv[nt];
      }
      #pragma unroll
      for (int ks = 0; ks < 4; ++ks){
        #pragma unroll
        for (int nt = 0; nt < 4; ++nt){
          acc[nt] = __builtin_amdgcn_mfma_f32_16x16x32_f16(afr[ks], bfr[ks][nt], acc[nt], 0, 0, 0);
        }
      }
      // acc[nt][r]: h = nt*16 + l15, t = trow + q*4 + r  -> ring slot group
      const int tgs = (tile & 31)*4 + q;
      #pragma unroll
      for (int nt = 0; nt < 4; ++nt){
        UH2 lo, hi;
        lo.p = __builtin_amdgcn_cvt_pkrtz(acc[nt][0], acc[nt][1]);
        hi.p = __builtin_amdgcn_cvt_pkrtz(acc[nt][2], acc[nt][3]);
        uint2 pk; pk.x = lo.u; pk.y = hi.u;
        *(uint2*)&Ub[(tgs*64 + nt*16 + l15) * 4] = pk;
      }
      __threadfence_block();  // wave-level lgkmcnt drain: all lanes' ds_writes done
      if (lane == 0)
        __hip_atomic_store(&flg[tile], 1u, __ATOMIC_RELEASE, __HIP_MEMORY_SCOPE_WORKGROUP);
    }
    return;
  }

  // ---------------- Consumers: wave 0 (sel=0), wave 4 (sel=1) --------------
  h16x2 w[32];
  {
    const uint4* wr = (const uint4*)(whf + lane * 32);
    #pragma unroll
    for (int j4 = 0; j4 < 8; ++j4){
      uint4 v = wr[j4];
      UH2 c0, c1, c2, c3;
      c0.u = v.x; c1.u = v.y; c2.u = v.z; c3.u = v.w;
      w[4*j4+0] = c0.h; w[4*j4+1] = c1.h; w[4*j4+2] = c2.h; w[4*j4+3] = c3.h;
    }
  }

  // Wait for tile 0 before the initial u loads.
  while (!__hip_atomic_load(&flg[0], __ATOMIC_ACQUIRE, __HIP_MEMORY_SCOPE_WORKGROUP)) {}

  const h16x4* Ul = (const h16x4*)Us + sel * 8192;  // ring entry = (tg&127)*64 + lane
  h16x4 uc = Ul[0*64 + lane];
  h16x4 u1 = Ul[1*64 + lane];

  float h = 0.0f;
  int last_ready = 0;
  #pragma unroll 1
  for (int tile = 0; tile < 64; ++tile){
    int wt = tile + 1; if (wt > 63) wt = 63;
    if (wt > last_ready){
      while (!__hip_atomic_load(&flg[wt], __ATOMIC_ACQUIRE, __HIP_MEMORY_SCOPE_WORKGROUP)) {}
      last_ready = wt;
    }
    #pragma unroll
    for (int tgl = 0; tgl < 4; ++tgl){
      const int tg = tile*4 + tgl;
      int tp = tg + 2; if (tp > TT/4 - 1) tp = TT/4 - 1;
      h16x4 u2 = Ul[(tp & 127)*64 + lane];
      float ug0 = (float)uc[0], ug1 = (float)uc[1], ug2 = (float)uc[2], ug3 = (float)uc[3];
      #pragma unroll
      for (int g = 0; g < 4; ++g){
        float ugv = (g==0) ? ug0 : (g==1) ? ug1 : (g==2) ? ug2 : ug3;
        // neighbor h via DPP quad-perm [1,0,3,2] (VALU pipe)
        unsigned nbu = (unsigned)__builtin_amdgcn_mov_dpp(__float_as_uint(h), 0xB1, 0xF, 0xF, true);
        UH2 hp; hp.p = __builtin_amdgcn_cvt_pkrtz(h, __uint_as_float(nbu)); // valid on even lanes
        const unsigned hpu = hp.u;
        float a0 = ugv, a1 = 0.0f, a2 = 0.0f, a3 = 0.0f;
        #pragma unroll
        for (int jp = 0; jp < 32; jp += 4){
          UH2 b0, b1, b2, b3;
          b0.u = (unsigned)__builtin_amdgcn_readlane(hpu, 2*jp + 0);
          b1.u = (unsigned)__builtin_amdgcn_readlane(hpu, 2*jp + 2);
          b2.u = (unsigned)__builtin_amdgcn_readlane(hpu, 2*jp + 4);
          b3.u = (unsigned)__builtin_amdgcn_readlane(hpu, 2*jp + 6);
          a0 = fdot2f(w[jp+0], b0.h, a0);
          a1 = fdot2f(w[jp+1], b1.h, a1);
          a2 = fdot2f(w[jp+2], b2.h, a2);
          a3 = fdot2f(w[jp+3], b3.h, a3);
        }
        h = tanh_pre((a0 + a1) + (a2 + a3));
      }
      uc = u1; u1 = u2;
    }
    // publish progress: release drains this wave's outstanding LDS reads, so
    // producers may safely reuse slots of tiles <= tile-30 afterwards.
    if (lane == 0)
      __hip_atomic_store(&cons[sel], (unsigned)(tile + 1), __ATOMIC_RELEASE, __HIP_MEMORY_SCOPE_WORKGROUP);
  }

  // Epilogue: predictions[b] = W_out @ h + W_out_b ; hidden[b] = h
  const int b = 2*blockIdx.x + sel;
  unsigned hu = __float_as_uint(h);
  float p0 = Woutb[lane];
  float p1 = Woutb[lane + 64];
  #pragma unroll 8
  for (int j = 0; j < 64; ++j){
    float hj = __uint_as_float(__builtin_amdgcn_readlane(hu, j));
    p0 = __builtin_fmaf(Wout[lane * HH + j],        hj, p0);
    p1 = __builtin_fmaf(Wout[(lane + 64) * HH + j], hj, p1);
  }
  out[b * 128 + lane]           = p0;
  out[b * 128 + 64 + lane]      = p1;
  out[BB * 128 + b * 64 + lane] = h;
}

// ---------------------------------------------------------------------------
extern "C" void kernel_launch(void* const* d_in, const int* in_sizes, int n_in,
                              void* d_out, int out_size, void* d_ws, size_t ws_size,
                              hipStream_t stream){
  const float* x     = (const float*)d_in[0];
  const float* Ap    = (const float*)d_in[1];
  const float* Am    = (const float*)d_in[2];
  const float* Winw  = (const float*)d_in[3];
  const float* Winb  = (const float*)d_in[4];
  const float* Woutw = (const float*)d_in[5];
  const float* Woutb = (const float*)d_in[6];
  const float* bias  = (const float*)d_in[7];

  float*          wsf = (float*)d_ws;
  unsigned*       whf = (unsigned*)((char*)d_ws + 16640);
  unsigned short* wsb = (unsigned short*)((char*)d_ws + 24832);

  float* out = (float*)d_out;

  hipFuncSetAttribute((const void*)k_fused,
                      hipFuncAttributeMaxDynamicSharedMemorySize, 131592);

  hipLaunchKernelGGL(k_prep,  dim3(1),      dim3(256), 0,      stream, Ap, Am, Winw, Winb, bias, wsf, whf, wsb);
  hipLaunchKernelGGL(k_fused, dim3(BB/2),   dim3(512), 131592, stream, x, wsf, whf, wsb, Woutw, Woutb, out);
}

// Round 3
// 339.471 us; speedup vs baseline: 1.3716x; 1.3716x over previous
//
#include <hip/hip_runtime.h>
#include <hip/hip_bf16.h>

// Problem constants
#define BB 256
#define TT 1024
#define II 128
#define HH 64

// 2/ln2 folded into W_comm, W_in and biases at prep time, so the recurrence
// computes tanh(x) as 1 - 2/(1+exp2(acc)) with no per-step pre-multiply.
#define PRESCALE 2.8853900817779268f

typedef float    f32x4_t __attribute__((ext_vector_type(4)));
typedef _Float16 h16x2   __attribute__((ext_vector_type(2)));
typedef _Float16 h16x4   __attribute__((ext_vector_type(4)));
typedef _Float16 h16x8   __attribute__((ext_vector_type(8)));
typedef __fp16   p16x2   __attribute__((ext_vector_type(2)));

union UH2 { unsigned u; h16x2 h; p16x2 p; };
union U4H8 { uint4 u; h16x8 h; };
union B128 { uint4 u; h16x2 h[4]; };

__device__ __forceinline__ float tanh_pre(float a){
  // input pre-scaled by 2/ln2: tanh = 1 - 2/(1+2^a)
  float e = __builtin_amdgcn_exp2f(a);
  return __builtin_fmaf(-2.0f, __builtin_amdgcn_rcpf(1.0f + e), 1.0f);
}

#if __has_builtin(__builtin_amdgcn_fdot2)
__device__ __forceinline__ float fdot2f(h16x2 a, h16x2 b, float c){
  return __builtin_amdgcn_fdot2(a, b, c, false);
}
#else
__device__ __forceinline__ float fdot2f(h16x2 a, h16x2 b, float c){
  return __builtin_fmaf((float)a[1], (float)b[1], __builtin_fmaf((float)a[0], (float)b[0], c));
}
#endif

// ---------------------------------------------------------------------------
// Workspace layout:
//   wsf (f32)  @ 0      [4160]: W_comm 64x64 row-major + combined bias[64] (all x PRESCALE)
//   whf (u32)  @ 16640  [2048]: W_comm rows as packed f16x2 pairs
//   wsb (u16)  @ 24832  [8192]: W_in f16 MFMA B-fragments, frag-ready (x PRESCALE)
// ---------------------------------------------------------------------------
__global__ void k_prep(const float* __restrict__ Ap, const float* __restrict__ Am,
                       const float* __restrict__ Winw,
                       const float* __restrict__ Winb, const float* __restrict__ bias,
                       float* __restrict__ wsf, unsigned* __restrict__ whf,
                       unsigned short* __restrict__ wsb){
  const int tid = threadIdx.x;
  for (int e = tid; e < 4096; e += 256){
    int i = e >> 6, j = e & 63;
    int is = i ^ 32, js = j ^ 32;
    float wp = Ap[i*64+j] + Ap[i*64+js] + Ap[is*64+j] + Ap[is*64+js];
    float wm = Am[i*64+j] - Am[i*64+js] - Am[is*64+j] + Am[is*64+js];
    wsf[e] = 0.25f * (wp + wm) * PRESCALE;
  }
  if (tid < 64) wsf[4096 + tid] = (Winb[tid] + bias[tid]) * PRESCALE;
  for (int e = tid; e < 8192; e += 256){
    int j = e & 7, lane = (e >> 3) & 63, fidx = e >> 9;
    int ks = fidx >> 2, nt = fidx & 3, l15 = lane & 15, q = lane >> 4;
    union { _Float16 f; unsigned short s; } cv;
    cv.f = (_Float16)(Winw[(nt*16 + l15)*II + ks*32 + q*8 + j] * PRESCALE);
    wsb[e] = cv.s;
  }
  __syncthreads();
  for (int e = tid; e < 2048; e += 256){
    int i = e >> 5, jp = e & 31;
    UH2 p;
    p.h[0] = (_Float16)wsf[i*64 + 2*jp];
    p.h[1] = (_Float16)wsf[i*64 + 2*jp + 1];
    whf[e] = p.u;
  }
}

// ---------------------------------------------------------------------------
// Fused producer/consumer kernel: one block per batch (256 blocks x 256 thr),
// round-0 geometry (proven). Consumer broadcast of h goes through LDS
// (write 128B of packed f16 pairs, read back with 8 uniform ds_read_b128
// broadcasts) instead of 32 v_readlane per step — the readlanes were
// measured (R0+R1) to occupy the VALU pipe ~8 cyc each, saturating the SIMD.
// R2 failed because the compiler hoisted the uniform LDS reads above the
// h ds_write (TBAA: unsigned vs uint4, no ordering edge). DS ops from one
// wave execute in order at the LDS, so a COMPILER barrier (asm memory
// clobber + sched_barrier) between write and reads is sufficient and free.
// ---------------------------------------------------------------------------
__global__ __launch_bounds__(256, 1) void k_fused(const float* __restrict__ x,
                                                  const float* __restrict__ wsf,
                                                  const unsigned* __restrict__ whf,
                                                  const unsigned short* __restrict__ wsb,
                                                  const float* __restrict__ Wout,
                                                  const float* __restrict__ Woutb,
                                                  float* __restrict__ out){
  extern __shared__ unsigned char smem[];
  unsigned short* Us    = (unsigned short*)smem;          // 128 KB U buffer
  unsigned*       flags = (unsigned*)(smem + 131072);     // 64 tile flags
  unsigned*       Hb    = (unsigned*)(smem + 131072 + 256); // 128B h broadcast

  const int b    = blockIdx.x;
  const int tid  = threadIdx.x;
  const int lane = tid & 63;
  const int wave = tid >> 6;
  const int l15  = lane & 15;
  const int q    = lane >> 4;

  if (tid < 64) flags[tid] = 0u;
  __syncthreads();

  if (wave != 0){
    // ---------------- Producers: waves 1..3 ----------------
    h16x8 bfr[4][4]; // [ks][nt]
    #pragma unroll
    for (int ks = 0; ks < 4; ++ks)
      #pragma unroll
      for (int nt = 0; nt < 4; ++nt)
        bfr[ks][nt] = *(const h16x8*)(wsb + ((ks*4 + nt)*64 + lane)*8);

    float bcv[4];
    #pragma unroll
    for (int nt = 0; nt < 4; ++nt) bcv[nt] = wsf[4096 + nt*16 + l15];

    const float* xb = x + (long)b * (TT * II);

    #pragma unroll 1
    for (int tile = wave - 1; tile < 64; tile += 3){
      const int trow = tile * 16;
      const float* xa = xb + (trow + l15) * II + q*8;
      h16x8 afr[4];
      #pragma unroll
      for (int ks = 0; ks < 4; ++ks){
        float4 a0 = *(const float4*)(xa + ks*32);
        float4 a1 = *(const float4*)(xa + ks*32 + 4);
        U4H8 v;
        UH2 p0, p1, p2, p3;
        p0.p = __builtin_amdgcn_cvt_pkrtz(a0.x, a0.y);
        p1.p = __builtin_amdgcn_cvt_pkrtz(a0.z, a0.w);
        p2.p = __builtin_amdgcn_cvt_pkrtz(a1.x, a1.y);
        p3.p = __builtin_amdgcn_cvt_pkrtz(a1.z, a1.w);
        v.u.x = p0.u; v.u.y = p1.u; v.u.z = p2.u; v.u.w = p3.u;
        afr[ks] = v.h;
      }
      f32x4_t acc[4];
      #pragma unroll
      for (int nt = 0; nt < 4; ++nt){
        acc[nt][0]=bcv[nt]; acc[nt][1]=bcv[nt]; acc[nt][2]=bcv[nt]; acc[nt][3]=bcv[nt];
      }
      #pragma unroll
      for (int ks = 0; ks < 4; ++ks){
        #pragma unroll
        for (int nt = 0; nt < 4; ++nt){
          acc[nt] = __builtin_amdgcn_mfma_f32_16x16x32_f16(afr[ks], bfr[ks][nt], acc[nt], 0, 0, 0);
        }
      }
      // acc[nt][r]: h = nt*16 + l15, t = trow + q*4 + r  -> tg = tile*4 + q
      const int tg = tile*4 + q;
      #pragma unroll
      for (int nt = 0; nt < 4; ++nt){
        UH2 lo, hi;
        lo.p = __builtin_amdgcn_cvt_pkrtz(acc[nt][0], acc[nt][1]);
        hi.p = __builtin_amdgcn_cvt_pkrtz(acc[nt][2], acc[nt][3]);
        uint2 pk; pk.x = lo.u; pk.y = hi.u;
        *(uint2*)&Us[(tg*64 + nt*16 + l15) * 4] = pk;
      }
      __threadfence_block();  // wave-level lgkmcnt drain: all lanes' ds_writes done
      if (lane == 0)
        __hip_atomic_store(&flags[tile], 1u, __ATOMIC_RELEASE, __HIP_MEMORY_SCOPE_WORKGROUP);
    }
    return;
  }

  // ---------------- Consumer: wave 0 ----------------
  h16x2 w[32];
  {
    const uint4* wr = (const uint4*)(whf + lane * 32);
    #pragma unroll
    for (int j4 = 0; j4 < 8; ++j4){
      uint4 v = wr[j4];
      UH2 c0, c1, c2, c3;
      c0.u = v.x; c1.u = v.y; c2.u = v.z; c3.u = v.w;
      w[4*j4+0] = c0.h; w[4*j4+1] = c1.h; w[4*j4+2] = c2.h; w[4*j4+3] = c3.h;
    }
  }

  // Wait for tile 0 before the initial u loads.
  while (!__hip_atomic_load(&flags[0], __ATOMIC_ACQUIRE, __HIP_MEMORY_SCOPE_WORKGROUP)) {}

  const h16x4* Ul = (const h16x4*)Us;  // entry index = tg*64 + lane
  h16x4 uc = Ul[0*64 + lane];
  h16x4 u1 = Ul[1*64 + lane];

  const bool wlane = !(lane & 1);      // even lanes own the packed h pair

  float h = 0.0f;
  int last_ready = 0;
  #pragma unroll 1
  for (int tile = 0; tile < 64; ++tile){
    int wt = tile + 1; if (wt > 63) wt = 63;
    if (wt > last_ready){
      while (!__hip_atomic_load(&flags[wt], __ATOMIC_ACQUIRE, __HIP_MEMORY_SCOPE_WORKGROUP)) {}
      last_ready = wt;
    }
    #pragma unroll
    for (int tgl = 0; tgl < 4; ++tgl){
      const int tg = tile*4 + tgl;
      int tp = tg + 2; if (tp > TT/4 - 1) tp = TT/4 - 1;
      h16x4 u2 = Ul[tp*64 + lane];
      float ug0 = (float)uc[0], ug1 = (float)uc[1], ug2 = (float)uc[2], ug3 = (float)uc[3];
      #pragma unroll
      for (int g = 0; g < 4; ++g){
        float ugv = (g==0) ? ug0 : (g==1) ? ug1 : (g==2) ? ug2 : ug3;
        // pack (h[2k], h[2k+1]) on even lanes via DPP quad-perm [1,0,3,2]
        unsigned nbu = (unsigned)__builtin_amdgcn_mov_dpp(__float_as_uint(h), 0xB1, 0xF, 0xF, true);
        UH2 hp; hp.p = __builtin_amdgcn_cvt_pkrtz(h, __uint_as_float(nbu)); // valid on even lanes
        if (wlane) Hb[lane >> 1] = hp.u;   // 32 lanes -> 128B, 1 lane/bank
        // Ordering fence: DS ops from this wave execute in-order at the LDS,
        // but the COMPILER must not hoist the uniform reads above the write
        // (this was R2's miscompile). Memory clobber + sched_barrier = free.
        __asm__ volatile("" ::: "memory");
        __builtin_amdgcn_sched_barrier(0);
        // read back the full h vector: 8 uniform-address b128 broadcasts
        B128 hv[8];
        const uint4* Hr = (const uint4*)Hb;
        #pragma unroll
        for (int r = 0; r < 8; ++r) hv[r].u = Hr[r];
        float a0 = ugv, a1 = 0.0f, a2 = 0.0f, a3 = 0.0f;
        #pragma unroll
        for (int jp = 0; jp < 32; jp += 4){
          a0 = fdot2f(w[jp+0], hv[(jp+0)>>2].h[(jp+0)&3], a0);
          a1 = fdot2f(w[jp+1], hv[(jp+1)>>2].h[(jp+1)&3], a1);
          a2 = fdot2f(w[jp+2], hv[(jp+2)>>2].h[(jp+2)&3], a2);
          a3 = fdot2f(w[jp+3], hv[(jp+3)>>2].h[(jp+3)&3], a3);
        }
        h = tanh_pre((a0 + a1) + (a2 + a3));
      }
      uc = u1; u1 = u2;
    }
  }

  // Epilogue: predictions[b] = W_out @ h + W_out_b ; hidden[b] = h
  unsigned hu = __float_as_uint(h);
  float p0 = Woutb[lane];
  float p1 = Woutb[lane + 64];
  #pragma unroll 8
  for (int j = 0; j < 64; ++j){
    float hj = __uint_as_float(__builtin_amdgcn_readlane(hu, j));
    p0 = __builtin_fmaf(Wout[lane * HH + j],        hj, p0);
    p1 = __builtin_fmaf(Wout[(lane + 64) * HH + j], hj, p1);
  }
  out[b * 128 + lane]           = p0;
  out[b * 128 + 64 + lane]      = p1;
  out[BB * 128 + b * 64 + lane] = h;
}

// ---------------------------------------------------------------------------
extern "C" void kernel_launch(void* const* d_in, const int* in_sizes, int n_in,
                              void* d_out, int out_size, void* d_ws, size_t ws_size,
                              hipStream_t stream){
  const float* x     = (const float*)d_in[0];
  const float* Ap    = (const float*)d_in[1];
  const float* Am    = (const float*)d_in[2];
  const float* Winw  = (const float*)d_in[3];
  const float* Winb  = (const float*)d_in[4];
  const float* Woutw = (const float*)d_in[5];
  const float* Woutb = (const float*)d_in[6];
  const float* bias  = (const float*)d_in[7];

  float*          wsf = (float*)d_ws;
  unsigned*       whf = (unsigned*)((char*)d_ws + 16640);
  unsigned short* wsb = (unsigned short*)((char*)d_ws + 24832);

  float* out = (float*)d_out;

  hipFuncSetAttribute((const void*)k_fused,
                      hipFuncAttributeMaxDynamicSharedMemorySize, 131456);

  hipLaunchKernelGGL(k_prep,  dim3(1),   dim3(256), 0,      stream, Ap, Am, Winw, Winb, bias, wsf, whf, wsb);
  hipLaunchKernelGGL(k_fused, dim3(BB),  dim3(256), 131456, stream, x, wsf, whf, wsb, Woutw, Woutb, out);
}

// Round 5
// 311.442 us; speedup vs baseline: 1.4950x; 1.0900x over previous
//
#include <hip/hip_runtime.h>
#include <hip/hip_bf16.h>

// Problem constants
#define BB 256
#define TT 1024
#define II 128
#define HH 64

// 2/ln2 folded into M+/M-, W_in and biases at prep time, so the recurrence
// computes tanh(x) as 1 - 2/(1+exp2(acc)) with no per-step pre-multiply.
#define PRESCALE 2.8853900817779268f

typedef float    f32x4_t __attribute__((ext_vector_type(4)));
typedef _Float16 h16x2   __attribute__((ext_vector_type(2)));
typedef _Float16 h16x4   __attribute__((ext_vector_type(4)));
typedef _Float16 h16x8   __attribute__((ext_vector_type(8)));
typedef __fp16   p16x2   __attribute__((ext_vector_type(2)));

union UH2 { unsigned u; h16x2 h; p16x2 p; };
union U4H8 { uint4 u; h16x8 h; };
union B128 { uint4 u; h16x2 h[4]; };

__device__ __forceinline__ float tanh_pre(float a){
  // input pre-scaled by 2/ln2: tanh = 1 - 2/(1+2^a)
  float e = __builtin_amdgcn_exp2f(a);
  return __builtin_fmaf(-2.0f, __builtin_amdgcn_rcpf(1.0f + e), 1.0f);
}

#if __has_builtin(__builtin_amdgcn_fdot2)
__device__ __forceinline__ float fdot2f(h16x2 a, h16x2 b, float c){
  return __builtin_amdgcn_fdot2(a, b, c, false);
}
#else
__device__ __forceinline__ float fdot2f(h16x2 a, h16x2 b, float c){
  return __builtin_fmaf((float)a[1], (float)b[1], __builtin_fmaf((float)a[0], (float)b[0], c));
}
#endif

// half_swap: value of v from lane (i ^ 32).
// permlane32_swap(v, v) returns {r0, r1} where per-lane {r0, r1} = {v, v_xor32}
// in an orientation-dependent order (R4 failed by picking the wrong one).
// r0 ^ r1 ^ v is exact at the bit level and recovers v_xor32 REGARDLESS of
// orientation: one of r0/r1 is v, the other is v_xor32. Compiles to
// permlane32_swap + v_xor3_b32.
#if __has_builtin(__builtin_amdgcn_permlane32_swap)
__device__ __forceinline__ float half_swap(float v){
  unsigned vu = __float_as_uint(v);
  auto r = __builtin_amdgcn_permlane32_swap(vu, vu, false, false);
  return __uint_as_float(((unsigned)r[0]) ^ ((unsigned)r[1]) ^ vu);
}
#else
__device__ __forceinline__ float half_swap(float v){
  return __shfl_xor(v, 32, 64);
}
#endif

// ---------------------------------------------------------------------------
// Workspace layout:
//   wsf (f32)  @ 0      [4160]: only [4096..4159] used: combined bias[64] x PRESCALE
//   whf (u32)  @ 16640  [1024]: M+/M- 32x32 rows as packed f16x2 pairs:
//                               lane<32 -> M+ row lane; lane>=32 -> M- row lane-32
//                               whf[lane*16 + jp] = (M[row][2jp], M[row][2jp+1])
//   wsb (u16)  @ 24832  [8192]: W_in f16 MFMA B-fragments, frag-ready (x PRESCALE)
//
// Z2 block-diagonalization: W_comm = P+ A+ P+ + P- A- P-  factors exactly as
//   W h = [ M+ s + M- d ; M+ s - M- d ],  s = h_lo + h_hi, d = h_lo - h_hi,
//   M+ = (A+_11 + A+_12 + A+_21 + A+_22)/4, M- = (A-_11 - A-_12 - A-_21 + A-_22)/4.
// Lanes 0-31 compute z1 = M+ s (16 fdot2), lanes 32-63 z2 = M- d; one
// half_swap + fma recombines. Halves the serial dot work + broadcast.
// ---------------------------------------------------------------------------
__global__ void k_prep(const float* __restrict__ Ap, const float* __restrict__ Am,
                       const float* __restrict__ Winw,
                       const float* __restrict__ Winb, const float* __restrict__ bias,
                       float* __restrict__ wsf, unsigned* __restrict__ whf,
                       unsigned short* __restrict__ wsb){
  const int tid = threadIdx.x;
  if (tid < 64) wsf[4096 + tid] = (Winb[tid] + bias[tid]) * PRESCALE;
  // M+/M- packed rows
  for (int e = tid; e < 1024; e += 256){
    int lane = e >> 4, jp = e & 15, row = lane & 31, j = 2*jp;
    float v0, v1;
    if (lane < 32){
      v0 = 0.25f*PRESCALE*(Ap[row*64+j]     + Ap[row*64+j+32]     + Ap[(row+32)*64+j]     + Ap[(row+32)*64+j+32]);
      v1 = 0.25f*PRESCALE*(Ap[row*64+j+1]   + Ap[row*64+j+33]     + Ap[(row+32)*64+j+1]   + Ap[(row+32)*64+j+33]);
    } else {
      v0 = 0.25f*PRESCALE*(Am[row*64+j]     - Am[row*64+j+32]     - Am[(row+32)*64+j]     + Am[(row+32)*64+j+32]);
      v1 = 0.25f*PRESCALE*(Am[row*64+j+1]   - Am[row*64+j+33]     - Am[(row+32)*64+j+1]   + Am[(row+32)*64+j+33]);
    }
    UH2 p;
    p.h[0] = (_Float16)v0;
    p.h[1] = (_Float16)v1;
    whf[e] = p.u;
  }
  for (int e = tid; e < 8192; e += 256){
    int j = e & 7, lane = (e >> 3) & 63, fidx = e >> 9;
    int ks = fidx >> 2, nt = fidx & 3, l15 = lane & 15, q = lane >> 4;
    union { _Float16 f; unsigned short s; } cv;
    cv.f = (_Float16)(Winw[(nt*16 + l15)*II + ks*32 + q*8 + j] * PRESCALE);
    wsb[e] = cv.s;
  }
}

// ---------------------------------------------------------------------------
// Fused producer/consumer kernel: one block per batch (256 blocks x 256 thr).
//   Producers (waves 1..3): 64 t-tiles (16 rows) round-robin — unchanged.
//   Consumer (wave 0): Z2-split recurrence. Per step:
//     half_swap(h) -> sd = h*sgn + hsw                 (s on lo, d on hi half)
//     DPP-pair-pack sd -> all-lane ds_write_b32 (slots 0..63, garbage in 32..63)
//     compiler fence -> 4 uniform ds_read_b128 per half (s @0B, d @64B)
//     16 fdot2 (4 chains x 4) -> z ; half_swap(z) -> a = z*sgn + zsw + u
//     h = tanh_pre(a)
// ---------------------------------------------------------------------------
__global__ __launch_bounds__(256, 1) void k_fused(const float* __restrict__ x,
                                                  const float* __restrict__ wsf,
                                                  const unsigned* __restrict__ whf,
                                                  const unsigned short* __restrict__ wsb,
                                                  const float* __restrict__ Wout,
                                                  const float* __restrict__ Woutb,
                                                  float* __restrict__ out){
  extern __shared__ unsigned char smem[];
  unsigned short* Us    = (unsigned short*)smem;            // 128 KB U buffer
  unsigned*       flags = (unsigned*)(smem + 131072);       // 64 tile flags
  unsigned*       Hb    = (unsigned*)(smem + 131072 + 256); // 256B sd broadcast

  const int b    = blockIdx.x;
  const int tid  = threadIdx.x;
  const int lane = tid & 63;
  const int wave = tid >> 6;
  const int l15  = lane & 15;
  const int q    = lane >> 4;

  if (tid < 64) flags[tid] = 0u;
  __syncthreads();

  if (wave != 0){
    // ---------------- Producers: waves 1..3 (unchanged, proven) ------------
    h16x8 bfr[4][4]; // [ks][nt]
    #pragma unroll
    for (int ks = 0; ks < 4; ++ks)
      #pragma unroll
      for (int nt = 0; nt < 4; ++nt)
        bfr[ks][nt] = *(const h16x8*)(wsb + ((ks*4 + nt)*64 + lane)*8);

    float bcv[4];
    #pragma unroll
    for (int nt = 0; nt < 4; ++nt) bcv[nt] = wsf[4096 + nt*16 + l15];

    const float* xb = x + (long)b * (TT * II);

    #pragma unroll 1
    for (int tile = wave - 1; tile < 64; tile += 3){
      const int trow = tile * 16;
      const float* xa = xb + (trow + l15) * II + q*8;
      h16x8 afr[4];
      #pragma unroll
      for (int ks = 0; ks < 4; ++ks){
        float4 a0 = *(const float4*)(xa + ks*32);
        float4 a1 = *(const float4*)(xa + ks*32 + 4);
        U4H8 v;
        UH2 p0, p1, p2, p3;
        p0.p = __builtin_amdgcn_cvt_pkrtz(a0.x, a0.y);
        p1.p = __builtin_amdgcn_cvt_pkrtz(a0.z, a0.w);
        p2.p = __builtin_amdgcn_cvt_pkrtz(a1.x, a1.y);
        p3.p = __builtin_amdgcn_cvt_pkrtz(a1.z, a1.w);
        v.u.x = p0.u; v.u.y = p1.u; v.u.z = p2.u; v.u.w = p3.u;
        afr[ks] = v.h;
      }
      f32x4_t acc[4];
      #pragma unroll
      for (int nt = 0; nt < 4; ++nt){
        acc[nt][0]=bcv[nt]; acc[nt][1]=bcv[nt]; acc[nt][2]=bcv[nt]; acc[nt][3]=bcv[nt];
      }
      #pragma unroll
      for (int ks = 0; ks < 4; ++ks){
        #pragma unroll
        for (int nt = 0; nt < 4; ++nt){
          acc[nt] = __builtin_amdgcn_mfma_f32_16x16x32_f16(afr[ks], bfr[ks][nt], acc[nt], 0, 0, 0);
        }
      }
      // acc[nt][r]: h = nt*16 + l15, t = trow + q*4 + r  -> tg = tile*4 + q
      const int tg = tile*4 + q;
      #pragma unroll
      for (int nt = 0; nt < 4; ++nt){
        UH2 lo, hi;
        lo.p = __builtin_amdgcn_cvt_pkrtz(acc[nt][0], acc[nt][1]);
        hi.p = __builtin_amdgcn_cvt_pkrtz(acc[nt][2], acc[nt][3]);
        uint2 pk; pk.x = lo.u; pk.y = hi.u;
        *(uint2*)&Us[(tg*64 + nt*16 + l15) * 4] = pk;
      }
      __threadfence_block();  // wave-level lgkmcnt drain: all lanes' ds_writes done
      if (lane == 0)
        __hip_atomic_store(&flags[tile], 1u, __ATOMIC_RELEASE, __HIP_MEMORY_SCOPE_WORKGROUP);
    }
    return;
  }

  // ---------------- Consumer: wave 0 ----------------
  // M+/M- row pairs for this lane (16 pairs = 32 f16)
  h16x2 w[16];
  {
    const uint4* wr = (const uint4*)(whf + lane * 16);
    #pragma unroll
    for (int j4 = 0; j4 < 4; ++j4){
      uint4 v = wr[j4];
      UH2 c0, c1, c2, c3;
      c0.u = v.x; c1.u = v.y; c2.u = v.z; c3.u = v.w;
      w[4*j4+0] = c0.h; w[4*j4+1] = c1.h; w[4*j4+2] = c2.h; w[4*j4+3] = c3.h;
    }
  }

  const bool  lo    = (lane < 32);
  const float sgn   = lo ? 1.0f : -1.0f;
  const int   hslot = (lane >> 1) + (lane & 1) * 32;   // all-lane write slot (0..63)
  const uint4* Hr   = (const uint4*)((const unsigned char*)Hb + (lane & 32) * 2); // +0 / +64 B

  // Wait for tile 0 before the initial u loads.
  while (!__hip_atomic_load(&flags[0], __ATOMIC_ACQUIRE, __HIP_MEMORY_SCOPE_WORKGROUP)) {}

  const h16x4* Ul = (const h16x4*)Us;  // entry index = tg*64 + lane
  h16x4 uc = Ul[0*64 + lane];
  h16x4 u1 = Ul[1*64 + lane];

  float h = 0.0f;
  int last_ready = 0;
  #pragma unroll 1
  for (int tile = 0; tile < 64; ++tile){
    int wt = tile + 1; if (wt > 63) wt = 63;
    if (wt > last_ready){
      while (!__hip_atomic_load(&flags[wt], __ATOMIC_ACQUIRE, __HIP_MEMORY_SCOPE_WORKGROUP)) {}
      last_ready = wt;
    }
    #pragma unroll
    for (int tgl = 0; tgl < 4; ++tgl){
      const int tg = tile*4 + tgl;
      int tp = tg + 2; if (tp > TT/4 - 1) tp = TT/4 - 1;
      h16x4 u2 = Ul[tp*64 + lane];
      float ug0 = (float)uc[0], ug1 = (float)uc[1], ug2 = (float)uc[2], ug3 = (float)uc[3];
      #pragma unroll
      for (int g = 0; g < 4; ++g){
        float ugv = (g==0) ? ug0 : (g==1) ? ug1 : (g==2) ? ug2 : ug3;
        // sd: s = h_lo + h_hi (lanes<32), d = h_lo - h_hi (lanes>=32)
        float hsw = half_swap(h);
        float sd  = __builtin_fmaf(h, sgn, hsw);
        // pack (sd_2k, sd_2k+1) on even lanes via DPP quad-perm [1,0,3,2]
        unsigned nbu = (unsigned)__builtin_amdgcn_mov_dpp(__float_as_uint(sd), 0xB1, 0xF, 0xF, true);
        UH2 hp; hp.p = __builtin_amdgcn_cvt_pkrtz(sd, __uint_as_float(nbu)); // valid on even lanes
        Hb[hslot] = hp.u;   // all lanes write: slots 0..31 = s/d pairs, 32..63 garbage
        // Ordering fence: DS ops from this wave execute in-order at the LDS,
        // but the COMPILER must not hoist the uniform reads above the write.
        __asm__ volatile("" ::: "memory");
        __builtin_amdgcn_sched_barrier(0);
        // read back this half's 32 values: 4 uniform-address b128 broadcasts
        B128 hv[4];
        #pragma unroll
        for (int r = 0; r < 4; ++r) hv[r].u = Hr[r];
        float a0 = 0.0f, a1 = 0.0f, a2 = 0.0f, a3 = 0.0f;
        #pragma unroll
        for (int jp = 0; jp < 16; jp += 4){
          a0 = fdot2f(w[jp+0], hv[(jp+0)>>2].h[(jp+0)&3], a0);
          a1 = fdot2f(w[jp+1], hv[(jp+1)>>2].h[(jp+1)&3], a1);
          a2 = fdot2f(w[jp+2], hv[(jp+2)>>2].h[(jp+2)&3], a2);
          a3 = fdot2f(w[jp+3], hv[(jp+3)>>2].h[(jp+3)&3], a3);
        }
        float z = (a0 + a1) + (a2 + a3);     // z1 on lo half, z2 on hi half
        // recombine: y_lo = z1 + z2, y_hi = z1 - z2
        float zsw = half_swap(z);
        float a = __builtin_fmaf(z, sgn, zsw) + ugv;
        h = tanh_pre(a);
      }
      uc = u1; u1 = u2;
    }
  }

  // Epilogue: predictions[b] = W_out @ h + W_out_b ; hidden[b] = h
  unsigned hu = __float_as_uint(h);
  float p0 = Woutb[lane];
  float p1 = Woutb[lane + 64];
  #pragma unroll 8
  for (int j = 0; j < 64; ++j){
    float hj = __uint_as_float(__builtin_amdgcn_readlane(hu, j));
    p0 = __builtin_fmaf(Wout[lane * HH + j],        hj, p0);
    p1 = __builtin_fmaf(Wout[(lane + 64) * HH + j], hj, p1);
  }
  out[b * 128 + lane]           = p0;
  out[b * 128 + 64 + lane]      = p1;
  out[BB * 128 + b * 64 + lane] = h;
}

// ---------------------------------------------------------------------------
extern "C" void kernel_launch(void* const* d_in, const int* in_sizes, int n_in,
                              void* d_out, int out_size, void* d_ws, size_t ws_size,
                              hipStream_t stream){
  const float* x     = (const float*)d_in[0];
  const float* Ap    = (const float*)d_in[1];
  const float* Am    = (const float*)d_in[2];
  const float* Winw  = (const float*)d_in[3];
  const float* Winb  = (const float*)d_in[4];
  const float* Woutw = (const float*)d_in[5];
  const float* Woutb = (const float*)d_in[6];
  const float* bias  = (const float*)d_in[7];

  float*          wsf = (float*)d_ws;
  unsigned*       whf = (unsigned*)((char*)d_ws + 16640);
  unsigned short* wsb = (unsigned short*)((char*)d_ws + 24832);

  float* out = (float*)d_out;

  hipFuncSetAttribute((const void*)k_fused,
                      hipFuncAttributeMaxDynamicSharedMemorySize, 131584);

  hipLaunchKernelGGL(k_prep,  dim3(1),   dim3(256), 0,      stream, Ap, Am, Winw, Winb, bias, wsf, whf, wsb);
  hipLaunchKernelGGL(k_fused, dim3(BB),  dim3(256), 131584, stream, x, wsf, whf, wsb, Woutw, Woutb, out);
}